// Round 9
// baseline (63.857 us; speedup 1.0000x reference)
//
#include <hip/hip_runtime.h>
#include <hip/hip_bf16.h>
#include <stdint.h>

// MultiDense: out[b,s,:] = values[b,s,:] @ W[lookups[b]] + bias[lookups[b]]
// B=16384, S=4, IN=OUT=128, 64 experts.
//
// R9: kill the centralized compaction (R8 coop-launch failed: output was
// all-zero == launch error; R6's solo-block compaction ~6-8us on one CU).
//  K1 (512 blocks x 256): W fp32 -> bf16 in MFMA B-fragment order, whole chip.
//  K2 (2048 blocks = 64 experts x 32 chunks, consecutive blocks share expert
//     for XCD/L2 locality): each block scans its OWN 512-entry lookup slice
//     (2 coalesced loads/thread, ~8 matches, trivial LDS-atomic compact) and
//     runs the R6 MFMA body: each wave one 4-sample group (16 rows x 128
//     cols), A fp32->bf16 in-reg from values, B fragments from L2-resident
//     wsW, 32x mfma_f32_16x16x32_bf16, masked stores. No global atomics, no
//     lists, no cnt, no cross-block dependencies.

#define NDIMS   64
#define IN_DIM  128
#define OUT_DIM 128
#define BATCH   16384
#define SEQ     4
#define NCHUNK  32
#define CHUNK   (BATCH / NCHUNK)   // 512
#define THREADS 256
#define NWAVE   4

// d_ws layout: [0, 2097152) W bf16 fragment layout: 64 x 8192 x ushort
using bf16x8 = __attribute__((ext_vector_type(8))) __bf16;
using f32x4  = __attribute__((ext_vector_type(4))) float;

static __device__ inline uint16_t bf16bits(float f) {
    __bf16 h = (__bf16)f;                   // RNE convert
    return __builtin_bit_cast(uint16_t, h);
}

static __device__ inline bf16x8 cvt8(f32x4 v0, f32x4 v1) {
    bf16x8 r;
    r[0] = (__bf16)v0[0]; r[1] = (__bf16)v0[1];
    r[2] = (__bf16)v0[2]; r[3] = (__bf16)v0[3];
    r[4] = (__bf16)v1[0]; r[5] = (__bf16)v1[1];
    r[6] = (__bf16)v1[2]; r[7] = (__bf16)v1[3];
    return r;
}

// ---- K1: W convert. gid = global 16B-chunk id, 1 per thread (131072 total).
// chunk = (((nf*4+ks)*16+l15)*4+l4); wo[chunk*8+j] = W[k0+j][o],
// o = nf*16+l15, k0 = ks*32+l4*8.
__global__ __launch_bounds__(THREADS)
void wconv_kernel(const float* __restrict__ W,
                  unsigned short* __restrict__ wsW)
{
    int gid   = blockIdx.x * THREADS + threadIdx.x;   // 0..131071
    int e     = gid >> 11;
    int chunk = gid & 2047;
    int l4  = chunk & 3;
    int l15 = (chunk >> 2) & 15;
    int ks  = (chunk >> 6) & 3;
    int nf  = chunk >> 8;
    const float* We = W + (size_t)e * (IN_DIM * OUT_DIM);
    int o  = nf * 16 + l15;
    int k0 = ks * 32 + l4 * 8;
    unsigned short r[8];
    #pragma unroll
    for (int j = 0; j < 8; ++j)
        r[j] = bf16bits(We[(k0 + j) * OUT_DIM + o]);
    unsigned short* wo = wsW + (size_t)e * (IN_DIM * OUT_DIM);
    *(uint64_t*)(wo + chunk * 8)     = *(const uint64_t*)&r[0];
    *(uint64_t*)(wo + chunk * 8 + 4) = *(const uint64_t*)&r[4];
}

// ---- K2: scan-own-slice + gemm. Block (e, c): expert e = bid>>5 (consecutive
// blocks same expert), chunk c = bid&31 (512 lookups).
__global__ __launch_bounds__(THREADS, 4)
void gemm_kernel(const float* __restrict__ values,
                 const float* __restrict__ bias,
                 const int*   __restrict__ lookups,
                 const unsigned short* __restrict__ wsW,
                 float*       __restrict__ out)
{
    __shared__ unsigned short list[CHUNK];
    __shared__ int nm_sh;

    const int tid = threadIdx.x;
    const int e   = blockIdx.x >> 5;
    const int c   = blockIdx.x & (NCHUNK - 1);

    if (tid == 0) nm_sh = 0;
    __syncthreads();

    // scan this block's 512-entry slice for expert e (~8 matches expected)
    {
        const int cbase = c * CHUNK;
        #pragma unroll
        for (int t = 0; t < CHUNK / THREADS; ++t) {
            int idx = cbase + t * THREADS + tid;
            if (lookups[idx] == e) {
                int p = atomicAdd(&nm_sh, 1);
                list[p] = (unsigned short)idx;
            }
        }
    }
    __syncthreads();

    const int nm = nm_sh;
    if (nm == 0) return;

    const int lane = tid & 63;
    const int wid  = tid >> 6;
    const int l15  = lane & 15;
    const int l4   = lane >> 4;

    // B fragment base for this lane (L2-resident bf16 W in fragment order)
    const unsigned short* wb = wsW + (size_t)e * (IN_DIM * OUT_DIM) + (l15 * 4 + l4) * 8;

    float bias_c[8];
    #pragma unroll
    for (int nf = 0; nf < 8; ++nf) bias_c[nf] = bias[e * OUT_DIM + nf * 16 + l15];

    // each wave: groups of 4 samples (16 GEMM rows x 128 cols)
    for (int grp = wid; grp * 4 < nm; grp += NWAVE) {
        const int sbase = grp * 4;

        // A fragment: row = l15 -> sample sbase+(l15>>2), seq row l15&3
        int pos = sbase + (l15 >> 2);
        pos = pos < nm ? pos : nm - 1;                 // clamp tail (stores masked)
        int b = (int)list[pos];
        const float* pA = values + (size_t)(b * SEQ + (l15 & 3)) * IN_DIM + l4 * 8;

        f32x4 acc[8];
        #pragma unroll
        for (int nf = 0; nf < 8; ++nf) {
            f32x4 a;
            a[0] = bias_c[nf]; a[1] = bias_c[nf]; a[2] = bias_c[nf]; a[3] = bias_c[nf];
            acc[nf] = a;
        }

        #pragma unroll
        for (int ks = 0; ks < 4; ++ks) {
            f32x4 v0 = *(const f32x4*)(pA + ks * 32);
            f32x4 v1 = *(const f32x4*)(pA + ks * 32 + 4);
            bf16x8 afr = cvt8(v0, v1);
            #pragma unroll
            for (int nf = 0; nf < 8; ++nf) {
                const bf16x8 bfr = *(const bf16x8*)(wb + (nf * 4 + ks) * 512);
                acc[nf] = __builtin_amdgcn_mfma_f32_16x16x32_bf16(afr, bfr, acc[nf], 0, 0, 0);
            }
        }

        // store: D layout col = l15, row = l4*4 + r (row -> sample sbase+(row>>2))
        #pragma unroll
        for (int r = 0; r < 4; ++r) {
            int row  = l4 * 4 + r;
            int pos2 = sbase + (row >> 2);
            if (pos2 < nm) {
                int b2 = (int)list[pos2];
                float* po = out + (size_t)(b2 * SEQ + (row & 3)) * OUT_DIM + l15;
                #pragma unroll
                for (int nf = 0; nf < 8; ++nf) po[nf * 16] = acc[nf][r];
            }
        }
    }
}

extern "C" void kernel_launch(void* const* d_in, const int* in_sizes, int n_in,
                              void* d_out, int out_size, void* d_ws, size_t ws_size,
                              hipStream_t stream) {
    const float* values  = (const float*)d_in[0];
    const float* W       = (const float*)d_in[1];
    const float* bias    = (const float*)d_in[2];
    const int*   lookups = (const int*)d_in[3];
    float* out = (float*)d_out;

    unsigned short* wsW = (unsigned short*)d_ws;

    hipLaunchKernelGGL(wconv_kernel, dim3(512), dim3(THREADS), 0, stream,
                       W, wsW);
    hipLaunchKernelGGL(gemm_kernel, dim3(NDIMS * NCHUNK), dim3(THREADS), 0, stream,
                       values, bias, lookups, wsW, out);
}